// Round 8
// baseline (4026.258 us; speedup 1.0000x reference)
//
#include <hip/hip_runtime.h>
#include <hip/hip_bf16.h>

#define B_ 8192
#define S_ 256
#define D_ 32
#define H_ 256
#define E_ 32
#define BT 32
#define NTH 1024

typedef short bf16x8 __attribute__((ext_vector_type(8)));
typedef float f32x4 __attribute__((ext_vector_type(4)));

__device__ __forceinline__ unsigned short f2bf(float x) {
  __hip_bfloat16 h = __float2bfloat16(x);
  return *reinterpret_cast<unsigned short*>(&h);
}
__device__ __forceinline__ unsigned pack2bf(float a, float b) {
  return (unsigned)f2bf(a) | ((unsigned)f2bf(b) << 16);
}
__device__ __forceinline__ float lo_bf(unsigned u) { return __uint_as_float(u << 16); }
__device__ __forceinline__ float hi_bf(unsigned u) { return __uint_as_float(u & 0xffff0000u); }
__device__ __forceinline__ float bf2f(unsigned short u) {
  return __uint_as_float((unsigned)u << 16);
}
__device__ __forceinline__ float sigf_(float x) { return 1.f / (1.f + __expf(-x)); }
__device__ __forceinline__ float tanhf_(float x) {
  float e = __expf(-2.f * fabsf(x));
  float r = (1.f - e) / (1.f + e);
  return copysignf(r, x);
}

// ---------------- prep kernels ----------------

// Pack W [N][srcStride] f32 (cols srcOff..+255) into mfma B-frag order bf16:
// n = nt*16+(lane&15), k = kt*32+(lane>>4)*8+e; flat = ((nt*8+kt)*64+lane)*8+e
__global__ void packB_k(const float* __restrict__ src, unsigned short* __restrict__ dst,
                        int N, int srcStride, int srcOff) {
  int g = blockIdx.x * blockDim.x + threadIdx.x;
  int total = N * 256 / 8;
  if (g >= total) return;
  int lane = g & 63, kt = (g >> 6) & 7, nt = g >> 9;
  int n = nt * 16 + (lane & 15);
  int k = kt * 32 + (lane >> 4) * 8;
  const float* s = src + (size_t)n * srcStride + srcOff + k;
#pragma unroll
  for (int e = 0; e < 8; ++e) dst[(size_t)g * 8 + e] = f2bf(s[e]);
}

// ptab[tok][n] = sum_e aemb[tok][e] * W_ih0[n][256+e]
__global__ void ptab_k(const float* __restrict__ aemb, const float* __restrict__ Wih0,
                       float* __restrict__ ptab) {
  int n = blockIdx.x * blockDim.x + threadIdx.x;
  if (n >= 1024) return;
  for (int tok = 0; tok < 3; ++tok) {
    float acc = 0.f;
    for (int e = 0; e < E_; ++e)
      acc = fmaf(aemb[tok * E_ + e], Wih0[(size_t)n * 288 + 256 + e], acc);
    ptab[tok * 1024 + n] = acc;
  }
}

__global__ void actmask_k(const int* __restrict__ a, unsigned* __restrict__ m) {
  int b = blockIdx.x * blockDim.x + threadIdx.x;
  if (b >= B_) return;
  unsigned v = 0;
  for (int t = 0; t < D_; ++t) v |= (unsigned)(a[(size_t)b * D_ + t] & 1) << t;
  m[b] = v;
}

// ---------------- main persistent kernel ----------------

// h tile LDS address: [32 rows][256 bf16 cols], byte = row*512 + colbyte, XOR swizzle
__device__ __forceinline__ int haddr(int row, int colbyte) {
  return (row * 512 + colbyte) ^ ((row & 7) << 4);
}

// acc[m][g] += A(32x256 from Abuf) x B(nt = g*16 + wave).
// Wlane = Wp + wave*4096 + lane*8 (shorts). g-offset = 65536 shorts, kt-offset = 512.
template <int NG>
__device__ __forceinline__ void gemm_frag(f32x4 acc[2][NG], const unsigned short* __restrict__ Wlane,
                                          const char* __restrict__ Abuf, int l15, int l4) {
#pragma unroll
  for (int kt = 0; kt < 8; ++kt) {
    bf16x8 a0 = *(const bf16x8*)(Abuf + haddr(l15, kt * 64 + l4 * 16));
    bf16x8 a1 = *(const bf16x8*)(Abuf + haddr(16 + l15, kt * 64 + l4 * 16));
#pragma unroll
    for (int g = 0; g < NG; ++g) {
      bf16x8 b = *(const bf16x8*)(Wlane + g * 65536 + kt * 512);
      acc[0][g] = __builtin_amdgcn_mfma_f32_16x16x32_bf16(a0, b, acc[0][g], 0, 0, 0);
      acc[1][g] = __builtin_amdgcn_mfma_f32_16x16x32_bf16(a1, b, acc[1][g], 0, 0, 0);
    }
  }
}

__global__ __attribute__((amdgpu_flat_work_group_size(NTH, NTH), amdgpu_waves_per_eu(4, 4)))
void actor_main(const float* __restrict__ states,
                const unsigned short* __restrict__ seWP,
                const float* __restrict__ se_b,
                const unsigned short* __restrict__ W0sP,
                const float* __restrict__ b_ih0, const float* __restrict__ b_hh0,
                const unsigned short* __restrict__ Whh0P,
                const unsigned short* __restrict__ Wih1P,
                const unsigned short* __restrict__ Whh1P,
                const float* __restrict__ b_ih1, const float* __restrict__ b_hh1,
                const float* __restrict__ ptabw,   // [3][1024] f32
                const unsigned* __restrict__ amaskw,
                const float* __restrict__ headsW,  // [D][H][2] f32
                const float* __restrict__ headsb,  // [D][2] f32
                float* __restrict__ out) {
  __shared__ char stA[16384];
  __shared__ char h0s[16384];
  __shared__ char h1s[16384];
  __shared__ unsigned amask_s[BT];

  const int tid = threadIdx.x;
  const int lane = tid & 63, wave = tid >> 6;
  const int l15 = lane & 15, l4 = lane >> 4;
  const int b0 = blockIdx.x * BT;
  const int wbase = wave * 4096 + lane * 8;  // shorts, per-matrix lane base

  // ---- stage states tile -> stA (bf16, A-layout, swizzled). threads 0..511.
  if (tid < 512) {
    int row = tid >> 4, c0i = (tid & 15) * 16;
    const float* sp = states + (size_t)(b0 + row) * S_ + c0i;
    union { unsigned short us[8]; int4 v; } ck0, ck1;
#pragma unroll
    for (int e = 0; e < 8; ++e) ck0.us[e] = f2bf(sp[e]);
#pragma unroll
    for (int e = 0; e < 8; ++e) ck1.us[e] = f2bf(sp[8 + e]);
    *(int4*)(stA + haddr(row, c0i * 2)) = ck0.v;
    *(int4*)(stA + haddr(row, c0i * 2 + 16)) = ck1.v;
  }
  if (tid < BT) amask_s[tid] = amaskw[b0 + tid];
  __syncthreads();

  // ---- s_emb = relu(states @ seW.T + se_b) -> h1s.  wave w owns cols w*16..w*16+15.
  {
    f32x4 a1[2][1];
#pragma unroll
    for (int m = 0; m < 2; ++m) a1[m][0] = (f32x4){0.f, 0.f, 0.f, 0.f};
    gemm_frag<1>(a1, seWP + wbase, stA, l15, l4);
    float seb = se_b[wave * 16 + l15];
#pragma unroll
    for (int m = 0; m < 2; ++m)
#pragma unroll
      for (int r = 0; r < 4; ++r) {
        float v = fmaxf(a1[m][0][r] + seb, 0.f);
        *(unsigned short*)(h1s + haddr(m * 16 + l4 * 4 + r, (wave * 16 + l15) * 2)) = f2bf(v);
      }
  }
  __syncthreads();

  // ---- x0 = bias0 + s_emb @ W_ih0[:, :256].T  -> packed bf16 in 16 regs
  unsigned x0p[2][4][2];
  {
    f32x4 xa[2][4];
#pragma unroll
    for (int m = 0; m < 2; ++m)
#pragma unroll
      for (int g = 0; g < 4; ++g) xa[m][g] = (f32x4){0.f, 0.f, 0.f, 0.f};
    gemm_frag<4>(xa, W0sP + wbase, h1s, l15, l4);
#pragma unroll
    for (int g = 0; g < 4; ++g) {
      int n = g * 256 + wave * 16 + l15;
      float bias = b_ih0[n] + b_hh0[n];
#pragma unroll
      for (int m = 0; m < 2; ++m) {
        x0p[m][g][0] = pack2bf(xa[m][g][0] + bias, xa[m][g][1] + bias);
        x0p[m][g][1] = pack2bf(xa[m][g][2] + bias, xa[m][g][3] + bias);
      }
    }
  }
  __syncthreads();

  // ---- zero h0s/h1s
  for (int i = tid; i < 1024; i += NTH) {
    ((int4*)h0s)[i] = make_int4(0, 0, 0, 0);
    ((int4*)h1s)[i] = make_int4(0, 0, 0, 0);
  }
  __syncthreads();

  // ---- packed per-thread constants
  unsigned ptp[3][2], b1p[2];
#pragma unroll
  for (int tok = 0; tok < 3; ++tok)
#pragma unroll
    for (int j = 0; j < 2; ++j) {
      int n0 = (2 * j) * 256 + wave * 16 + l15, n1 = (2 * j + 1) * 256 + wave * 16 + l15;
      ptp[tok][j] = pack2bf(ptabw[tok * 1024 + n0], ptabw[tok * 1024 + n1]);
    }
#pragma unroll
  for (int j = 0; j < 2; ++j) {
    int n0 = (2 * j) * 256 + wave * 16 + l15, n1 = (2 * j + 1) * 256 + wave * 16 + l15;
    b1p[j] = pack2bf(b_ih1[n0] + b_hh1[n0], b_ih1[n1] + b_hh1[n1]);
  }

  float c0v[2][4], c1v[2][4];
#pragma unroll
  for (int m = 0; m < 2; ++m)
#pragma unroll
    for (int r = 0; r < 4; ++r) { c0v[m][r] = 0.f; c1v[m][r] = 0.f; }

  const int hrow = wave * 2 + (lane >> 5);
  const int l31 = lane & 31;
  const unsigned hmask = amask_s[hrow];
  float tlp = 0.f, tent = 0.f;

#pragma unroll 1
  for (int t = 0; t < D_; ++t) {
    // unpack ptab values for this step's token choices
    float p0g[4], p1g[4];
    if (t == 0) {
#pragma unroll
      for (int j = 0; j < 2; ++j) {
        p0g[2 * j] = lo_bf(ptp[2][j]); p0g[2 * j + 1] = hi_bf(ptp[2][j]);
        p1g[2 * j] = p0g[2 * j];       p1g[2 * j + 1] = p0g[2 * j + 1];
      }
    } else {
#pragma unroll
      for (int j = 0; j < 2; ++j) {
        p0g[2 * j] = lo_bf(ptp[0][j]); p0g[2 * j + 1] = hi_bf(ptp[0][j]);
        p1g[2 * j] = lo_bf(ptp[1][j]); p1g[2 * j + 1] = hi_bf(ptp[1][j]);
      }
    }

    // ==== layer 0: acc = x0 + ptab[tok] + h0 @ Whh0.T
    f32x4 acc[2][4];
#pragma unroll
    for (int m = 0; m < 2; ++m)
#pragma unroll
      for (int r = 0; r < 4; ++r) {
        unsigned msk = amask_s[m * 16 + l4 * 4 + r];  // LDS broadcast read
        bool hi1 = t ? (((msk >> (t - 1)) & 1u) != 0u) : false;
#pragma unroll
        for (int g = 0; g < 4; ++g) {
          float x0v = (r & 1) ? hi_bf(x0p[m][g][r >> 1]) : lo_bf(x0p[m][g][r >> 1]);
          acc[m][g][r] = x0v + (hi1 ? p1g[g] : p0g[g]);
        }
      }
    gemm_frag<4>(acc, Whh0P + wbase, h0s, l15, l4);

    unsigned short hn[2][4];
#pragma unroll
    for (int m = 0; m < 2; ++m)
#pragma unroll
      for (int r = 0; r < 4; ++r) {
        float ig = sigf_(acc[m][0][r]);
        float fg = sigf_(acc[m][1][r]);
        float gg = tanhf_(acc[m][2][r]);
        float og = sigf_(acc[m][3][r]);
        float c = fg * c0v[m][r] + ig * gg;
        c0v[m][r] = c;
        hn[m][r] = f2bf(og * tanhf_(c));
      }
    __syncthreads();  // everyone done reading old h0s
#pragma unroll
    for (int m = 0; m < 2; ++m)
#pragma unroll
      for (int r = 0; r < 4; ++r)
        *(unsigned short*)(h0s + haddr(m * 16 + l4 * 4 + r, (wave * 16 + l15) * 2)) = hn[m][r];
    __syncthreads();  // new h0s visible

    // ==== layer 1: acc = b1 + h0_new @ Wih1.T + h1_old @ Whh1.T
    float b1g0 = lo_bf(b1p[0]), b1g1 = hi_bf(b1p[0]);
    float b1g2 = lo_bf(b1p[1]), b1g3 = hi_bf(b1p[1]);
#pragma unroll
    for (int m = 0; m < 2; ++m) {
      acc[m][0] = (f32x4){b1g0, b1g0, b1g0, b1g0};
      acc[m][1] = (f32x4){b1g1, b1g1, b1g1, b1g1};
      acc[m][2] = (f32x4){b1g2, b1g2, b1g2, b1g2};
      acc[m][3] = (f32x4){b1g3, b1g3, b1g3, b1g3};
    }
    gemm_frag<4>(acc, Wih1P + wbase, h0s, l15, l4);
    gemm_frag<4>(acc, Whh1P + wbase, h1s, l15, l4);

#pragma unroll
    for (int m = 0; m < 2; ++m)
#pragma unroll
      for (int r = 0; r < 4; ++r) {
        float ig = sigf_(acc[m][0][r]);
        float fg = sigf_(acc[m][1][r]);
        float gg = tanhf_(acc[m][2][r]);
        float og = sigf_(acc[m][3][r]);
        float c = fg * c1v[m][r] + ig * gg;
        c1v[m][r] = c;
        hn[m][r] = f2bf(og * tanhf_(c));
      }
    __syncthreads();  // everyone done reading old h1s
#pragma unroll
    for (int m = 0; m < 2; ++m)
#pragma unroll
      for (int r = 0; r < 4; ++r)
        *(unsigned short*)(h1s + haddr(m * 16 + l4 * 4 + r, (wave * 16 + l15) * 2)) = hn[m][r];
    __syncthreads();  // new h1s visible

    // ==== heads: 32 lanes per row, row = wave*2 + (lane>>5)
    float p0 = 0.f, p1 = 0.f;
    const float* hw = headsW + (size_t)t * 512;
#pragma unroll
    for (int jj = 0; jj < 8; ++jj) {
      int j = l31 + jj * 32;
      float h = bf2f(*(const unsigned short*)(h1s + haddr(hrow, j * 2)));
      float2 w = *(const float2*)(hw + j * 2);
      p0 = fmaf(h, w.x, p0);
      p1 = fmaf(h, w.y, p1);
    }
#pragma unroll
    for (int mm = 1; mm < 32; mm <<= 1) {
      p0 += __shfl_xor(p0, mm, 64);
      p1 += __shfl_xor(p1, mm, 64);
    }
    float l0 = p0 + headsb[t * 2 + 0], l1 = p1 + headsb[t * 2 + 1];
    float mx = fmaxf(l0, l1);
    float e0 = __expf(l0 - mx), e1 = __expf(l1 - mx);
    float Z = e0 + e1;
    float lse = mx + __logf(Z);
    float lp0 = l0 - lse, lp1 = l1 - lse;
    float ent = -(e0 * lp0 + e1 * lp1) / Z;
    int a = (hmask >> t) & 1;
    float lp = a ? lp1 : lp0;
    if (l31 == 0) {
      int rowg = b0 + hrow;
      out[2 * B_ + (size_t)rowg * D_ + t] = tlp;  // prefix BEFORE adding
      out[2 * B_ + B_ * D_ + (size_t)rowg * D_ + t] = ent;
    }
    tlp += lp;
    tent += ent;
  }
  if (l31 == 0) {
    int rowg = b0 + hrow;
    out[rowg] = tlp;
    out[B_ + rowg] = tent;
  }
}

// ---------------- launcher ----------------

extern "C" void kernel_launch(void* const* d_in, const int* in_sizes, int n_in,
                              void* d_out, int out_size, void* d_ws, size_t ws_size,
                              hipStream_t stream) {
  const float* states = (const float*)d_in[0];
  const int* actions = (const int*)d_in[1];
  const float* se_W = (const float*)d_in[2];
  const float* se_b = (const float*)d_in[3];
  const float* aemb = (const float*)d_in[4];
  const float* W_ih0 = (const float*)d_in[5];
  const float* W_hh0 = (const float*)d_in[6];
  const float* b_ih0 = (const float*)d_in[7];
  const float* b_hh0 = (const float*)d_in[8];
  const float* W_ih1 = (const float*)d_in[9];
  const float* W_hh1 = (const float*)d_in[10];
  const float* b_ih1 = (const float*)d_in[11];
  const float* b_hh1 = (const float*)d_in[12];
  const float* headsW = (const float*)d_in[13];
  const float* headsb = (const float*)d_in[14];
  float* out = (float*)d_out;
  char* ws = (char*)d_ws;

  unsigned short* seWP  = (unsigned short*)(ws + 0);        // 131072 B
  unsigned short* W0sP  = (unsigned short*)(ws + 131072);   // 524288 B each
  unsigned short* Whh0P = (unsigned short*)(ws + 655360);
  unsigned short* Wih1P = (unsigned short*)(ws + 1179648);
  unsigned short* Whh1P = (unsigned short*)(ws + 1703936);
  float* ptabw          = (float*)(ws + 2228224);
  unsigned* amaskw      = (unsigned*)(ws + 2240512);

  hipLaunchKernelGGL(packB_k, dim3(32), dim3(256), 0, stream, se_W, seWP, 256, 256, 0);
  hipLaunchKernelGGL(packB_k, dim3(128), dim3(256), 0, stream, W_ih0, W0sP, 1024, 288, 0);
  hipLaunchKernelGGL(packB_k, dim3(128), dim3(256), 0, stream, W_hh0, Whh0P, 1024, 256, 0);
  hipLaunchKernelGGL(packB_k, dim3(128), dim3(256), 0, stream, W_ih1, Wih1P, 1024, 256, 0);
  hipLaunchKernelGGL(packB_k, dim3(128), dim3(256), 0, stream, W_hh1, Whh1P, 1024, 256, 0);
  hipLaunchKernelGGL(ptab_k, dim3(4), dim3(256), 0, stream, aemb, W_ih0, ptabw);
  hipLaunchKernelGGL(actmask_k, dim3(32), dim3(256), 0, stream, actions, amaskw);
  hipLaunchKernelGGL(actor_main, dim3(B_ / BT), dim3(NTH), 0, stream,
                     states, seWP, se_b, W0sP, b_ih0, b_hh0, Whh0P, Wih1P, Whh1P,
                     b_ih1, b_hh1, ptabw, amaskw, headsW, headsb, out);
}

// Round 9
// 3979.417 us; speedup vs baseline: 1.0118x; 1.0118x over previous
//
#include <hip/hip_runtime.h>
#include <hip/hip_bf16.h>

#define B_ 8192
#define S_ 256
#define D_ 32
#define H_ 256
#define E_ 32
#define BT 32
#define NTH 1024

typedef short bf16x8 __attribute__((ext_vector_type(8)));
typedef float f32x4 __attribute__((ext_vector_type(4)));

__device__ __forceinline__ unsigned short f2bf(float x) {
  __hip_bfloat16 h = __float2bfloat16(x);
  return *reinterpret_cast<unsigned short*>(&h);
}
__device__ __forceinline__ unsigned pack2bf(float a, float b) {
  return (unsigned)f2bf(a) | ((unsigned)f2bf(b) << 16);
}
__device__ __forceinline__ float lo_bf(unsigned u) { return __uint_as_float(u << 16); }
__device__ __forceinline__ float hi_bf(unsigned u) { return __uint_as_float(u & 0xffff0000u); }
__device__ __forceinline__ float bf2f(unsigned short u) {
  return __uint_as_float((unsigned)u << 16);
}
__device__ __forceinline__ float sigf_(float x) { return 1.f / (1.f + __expf(-x)); }
__device__ __forceinline__ float tanhf_(float x) {
  float e = __expf(-2.f * fabsf(x));
  float r = (1.f - e) / (1.f + e);
  return copysignf(r, x);
}

// ---------------- prep kernels ----------------

// Pack W [N][srcStride] f32 (cols srcOff..+255) into mfma B-frag order bf16:
// n = nt*16+(lane&15), k = kt*32+(lane>>4)*8+e; flat = ((nt*8+kt)*64+lane)*8+e
__global__ void packB_k(const float* __restrict__ src, unsigned short* __restrict__ dst,
                        int N, int srcStride, int srcOff) {
  int g = blockIdx.x * blockDim.x + threadIdx.x;
  int total = N * 256 / 8;
  if (g >= total) return;
  int lane = g & 63, kt = (g >> 6) & 7, nt = g >> 9;
  int n = nt * 16 + (lane & 15);
  int k = kt * 32 + (lane >> 4) * 8;
  const float* s = src + (size_t)n * srcStride + srcOff + k;
#pragma unroll
  for (int e = 0; e < 8; ++e) dst[(size_t)g * 8 + e] = f2bf(s[e]);
}

// ptab[tok][n] = sum_e aemb[tok][e] * W_ih0[n][256+e]
__global__ void ptab_k(const float* __restrict__ aemb, const float* __restrict__ Wih0,
                       float* __restrict__ ptab) {
  int n = blockIdx.x * blockDim.x + threadIdx.x;
  if (n >= 1024) return;
  for (int tok = 0; tok < 3; ++tok) {
    float acc = 0.f;
    for (int e = 0; e < E_; ++e)
      acc = fmaf(aemb[tok * E_ + e], Wih0[(size_t)n * 288 + 256 + e], acc);
    ptab[tok * 1024 + n] = acc;
  }
}

__global__ void actmask_k(const int* __restrict__ a, unsigned* __restrict__ m) {
  int b = blockIdx.x * blockDim.x + threadIdx.x;
  if (b >= B_) return;
  unsigned v = 0;
  for (int t = 0; t < D_; ++t) v |= (unsigned)(a[(size_t)b * D_ + t] & 1) << t;
  m[b] = v;
}

// ---------------- main persistent kernel ----------------

// h tile LDS address: [32 rows][256 bf16 cols], byte = row*512 + colbyte, XOR swizzle
__device__ __forceinline__ int haddr(int row, int colbyte) {
  return (row * 512 + colbyte) ^ ((row & 7) << 4);
}

// acc[m][g] += A(32x256 from Abuf) x B(nt = g*16 + wave).
// Wlane = Wp + wave*4096 + lane*8 (shorts). g-offset = 65536 shorts, kt-offset = 512.
template <int NG>
__device__ __forceinline__ void gemm_frag(f32x4 acc[2][NG], const unsigned short* __restrict__ Wlane,
                                          const char* __restrict__ Abuf, int l15, int l4) {
#pragma unroll
  for (int kt = 0; kt < 8; ++kt) {
    bf16x8 a0 = *(const bf16x8*)(Abuf + haddr(l15, kt * 64 + l4 * 16));
    bf16x8 a1 = *(const bf16x8*)(Abuf + haddr(16 + l15, kt * 64 + l4 * 16));
#pragma unroll
    for (int g = 0; g < NG; ++g) {
      bf16x8 b = *(const bf16x8*)(Wlane + g * 65536 + kt * 512);
      acc[0][g] = __builtin_amdgcn_mfma_f32_16x16x32_bf16(a0, b, acc[0][g], 0, 0, 0);
      acc[1][g] = __builtin_amdgcn_mfma_f32_16x16x32_bf16(a1, b, acc[1][g], 0, 0, 0);
    }
  }
}

__global__ __attribute__((amdgpu_flat_work_group_size(NTH, NTH), amdgpu_waves_per_eu(4, 4)))
void actor_main(const float* __restrict__ states,
                const unsigned short* __restrict__ seWP,
                const float* __restrict__ se_b,
                const unsigned short* __restrict__ W0sP,
                const float* __restrict__ b_ih0, const float* __restrict__ b_hh0,
                const unsigned short* __restrict__ Whh0P,
                const unsigned short* __restrict__ Wih1P,
                const unsigned short* __restrict__ Whh1P,
                const float* __restrict__ b_ih1, const float* __restrict__ b_hh1,
                const float* __restrict__ ptabw,   // [3][1024] f32
                const unsigned* __restrict__ amaskw,
                const float* __restrict__ headsW,  // [D][H][2] f32
                const float* __restrict__ headsb,  // [D][2] f32
                float* __restrict__ out) {
  __shared__ char h0s[16384];
  __shared__ char h1s[16384];
  // x0L: 64 KB. chunk c (c=0..3) holds 16 B per thread at byte c*16384 + tid*16.
  // During the prologue, chunk 0 region doubles as the states staging tile (stA).
  // Total LDS ~98.5 KB -> only 1 block/CU fits -> backend budgets VGPRs for
  // 16 waves/CU (4/EU) = 128 VGPRs instead of 64 (the round-8 spill cause).
  __shared__ char x0L[65536];
  __shared__ unsigned amask_s[BT];

  const int tid = threadIdx.x;
  const int lane = tid & 63, wave = tid >> 6;
  const int l15 = lane & 15, l4 = lane >> 4;
  const int b0 = blockIdx.x * BT;
  const int wbase = wave * 4096 + lane * 8;  // shorts, per-matrix lane base
  char* stA = x0L;                           // overlay: states tile lives in chunk 0

  // ---- stage states tile -> stA (bf16, A-layout, swizzled). threads 0..511.
  if (tid < 512) {
    int row = tid >> 4, c0i = (tid & 15) * 16;
    const float* sp = states + (size_t)(b0 + row) * S_ + c0i;
    union { unsigned short us[8]; int4 v; } ck0, ck1;
#pragma unroll
    for (int e = 0; e < 8; ++e) ck0.us[e] = f2bf(sp[e]);
#pragma unroll
    for (int e = 0; e < 8; ++e) ck1.us[e] = f2bf(sp[8 + e]);
    *(int4*)(stA + haddr(row, c0i * 2)) = ck0.v;
    *(int4*)(stA + haddr(row, c0i * 2 + 16)) = ck1.v;
  }
  if (tid < BT) amask_s[tid] = amaskw[b0 + tid];
  __syncthreads();

  // ---- s_emb = relu(states @ seW.T + se_b) -> h1s.  wave w owns cols w*16..w*16+15.
  {
    f32x4 a1[2][1];
#pragma unroll
    for (int m = 0; m < 2; ++m) a1[m][0] = (f32x4){0.f, 0.f, 0.f, 0.f};
    gemm_frag<1>(a1, seWP + wbase, stA, l15, l4);
    float seb = se_b[wave * 16 + l15];
#pragma unroll
    for (int m = 0; m < 2; ++m)
#pragma unroll
      for (int r = 0; r < 4; ++r) {
        float v = fmaxf(a1[m][0][r] + seb, 0.f);
        *(unsigned short*)(h1s + haddr(m * 16 + l4 * 4 + r, (wave * 16 + l15) * 2)) = f2bf(v);
      }
  }
  __syncthreads();  // stA reads complete; h1s (s_emb) visible

  // ---- x0 = bias0 + s_emb @ W_ih0[:, :256].T  -> packed bf16 in x0L (LDS)
  {
    f32x4 xa[2][4];
#pragma unroll
    for (int m = 0; m < 2; ++m)
#pragma unroll
      for (int g = 0; g < 4; ++g) xa[m][g] = (f32x4){0.f, 0.f, 0.f, 0.f};
    gemm_frag<4>(xa, W0sP + wbase, h1s, l15, l4);
    float bias[4];
#pragma unroll
    for (int g = 0; g < 4; ++g) {
      int n = g * 256 + wave * 16 + l15;
      bias[g] = b_ih0[n] + b_hh0[n];
    }
    // chunk c: m = c>>1, gbase = (c&1)*2. q = {g,g r01|r23, g+1 r01|r23}
#pragma unroll
    for (int c = 0; c < 4; ++c) {
      int m = c >> 1, gb = (c & 1) * 2;
      uint4 q;
      q.x = pack2bf(xa[m][gb][0] + bias[gb], xa[m][gb][1] + bias[gb]);
      q.y = pack2bf(xa[m][gb][2] + bias[gb], xa[m][gb][3] + bias[gb]);
      q.z = pack2bf(xa[m][gb + 1][0] + bias[gb + 1], xa[m][gb + 1][1] + bias[gb + 1]);
      q.w = pack2bf(xa[m][gb + 1][2] + bias[gb + 1], xa[m][gb + 1][3] + bias[gb + 1]);
      *(uint4*)(x0L + c * 16384 + tid * 16) = q;  // overwrites stA region (dead)
    }
  }
  __syncthreads();  // h1s reads complete; x0L visible

  // ---- zero h0s/h1s
  for (int i = tid; i < 1024; i += NTH) {
    ((int4*)h0s)[i] = make_int4(0, 0, 0, 0);
    ((int4*)h1s)[i] = make_int4(0, 0, 0, 0);
  }
  __syncthreads();

  // ---- packed per-thread constants
  unsigned ptp[3][2], b1p[2];
#pragma unroll
  for (int tok = 0; tok < 3; ++tok)
#pragma unroll
    for (int j = 0; j < 2; ++j) {
      int n0 = (2 * j) * 256 + wave * 16 + l15, n1 = (2 * j + 1) * 256 + wave * 16 + l15;
      ptp[tok][j] = pack2bf(ptabw[tok * 1024 + n0], ptabw[tok * 1024 + n1]);
    }
#pragma unroll
  for (int j = 0; j < 2; ++j) {
    int n0 = (2 * j) * 256 + wave * 16 + l15, n1 = (2 * j + 1) * 256 + wave * 16 + l15;
    b1p[j] = pack2bf(b_ih1[n0] + b_hh1[n0], b_ih1[n1] + b_hh1[n1]);
  }

  float c0v[2][4], c1v[2][4];
#pragma unroll
  for (int m = 0; m < 2; ++m)
#pragma unroll
    for (int r = 0; r < 4; ++r) { c0v[m][r] = 0.f; c1v[m][r] = 0.f; }

  const int hrow = wave * 2 + (lane >> 5);
  const int l31 = lane & 31;
  const unsigned hmask = amask_s[hrow];
  float tlp = 0.f, tent = 0.f;

#pragma unroll 1
  for (int t = 0; t < D_; ++t) {
    // unpack ptab values for this step's token choices
    float p0g[4], p1g[4];
    if (t == 0) {
#pragma unroll
      for (int j = 0; j < 2; ++j) {
        p0g[2 * j] = lo_bf(ptp[2][j]); p0g[2 * j + 1] = hi_bf(ptp[2][j]);
        p1g[2 * j] = p0g[2 * j];       p1g[2 * j + 1] = p0g[2 * j + 1];
      }
    } else {
#pragma unroll
      for (int j = 0; j < 2; ++j) {
        p0g[2 * j] = lo_bf(ptp[0][j]); p0g[2 * j + 1] = hi_bf(ptp[0][j]);
        p1g[2 * j] = lo_bf(ptp[1][j]); p1g[2 * j + 1] = hi_bf(ptp[1][j]);
      }
    }

    // re-read x0 (4 x ds_read_b128, conflict-free thread-major layout)
    unsigned xr[16];
#pragma unroll
    for (int c = 0; c < 4; ++c) {
      uint4 q = *(const uint4*)(x0L + c * 16384 + tid * 16);
      xr[c * 4 + 0] = q.x; xr[c * 4 + 1] = q.y; xr[c * 4 + 2] = q.z; xr[c * 4 + 3] = q.w;
    }

    // ==== layer 0: acc = x0 + ptab[tok] + h0 @ Whh0.T
    f32x4 acc[2][4];
#pragma unroll
    for (int m = 0; m < 2; ++m)
#pragma unroll
      for (int r = 0; r < 4; ++r) {
        unsigned msk = amask_s[m * 16 + l4 * 4 + r];  // LDS broadcast read
        bool hi1 = t ? (((msk >> (t - 1)) & 1u) != 0u) : false;
#pragma unroll
        for (int g = 0; g < 4; ++g) {
          unsigned u = xr[(m * 2 + (g >> 1)) * 4 + (g & 1) * 2 + (r >> 1)];
          float x0v = (r & 1) ? hi_bf(u) : lo_bf(u);
          acc[m][g][r] = x0v + (hi1 ? p1g[g] : p0g[g]);
        }
      }
    gemm_frag<4>(acc, Whh0P + wbase, h0s, l15, l4);

    unsigned short hn[2][4];
#pragma unroll
    for (int m = 0; m < 2; ++m)
#pragma unroll
      for (int r = 0; r < 4; ++r) {
        float ig = sigf_(acc[m][0][r]);
        float fg = sigf_(acc[m][1][r]);
        float gg = tanhf_(acc[m][2][r]);
        float og = sigf_(acc[m][3][r]);
        float c = fg * c0v[m][r] + ig * gg;
        c0v[m][r] = c;
        hn[m][r] = f2bf(og * tanhf_(c));
      }
    __syncthreads();  // everyone done reading old h0s
#pragma unroll
    for (int m = 0; m < 2; ++m)
#pragma unroll
      for (int r = 0; r < 4; ++r)
        *(unsigned short*)(h0s + haddr(m * 16 + l4 * 4 + r, (wave * 16 + l15) * 2)) = hn[m][r];
    __syncthreads();  // new h0s visible

    // ==== layer 1: acc = b1 + h0_new @ Wih1.T + h1_old @ Whh1.T
    float b1g0 = lo_bf(b1p[0]), b1g1 = hi_bf(b1p[0]);
    float b1g2 = lo_bf(b1p[1]), b1g3 = hi_bf(b1p[1]);
#pragma unroll
    for (int m = 0; m < 2; ++m) {
      acc[m][0] = (f32x4){b1g0, b1g0, b1g0, b1g0};
      acc[m][1] = (f32x4){b1g1, b1g1, b1g1, b1g1};
      acc[m][2] = (f32x4){b1g2, b1g2, b1g2, b1g2};
      acc[m][3] = (f32x4){b1g3, b1g3, b1g3, b1g3};
    }
    gemm_frag<4>(acc, Wih1P + wbase, h0s, l15, l4);
    gemm_frag<4>(acc, Whh1P + wbase, h1s, l15, l4);

#pragma unroll
    for (int m = 0; m < 2; ++m)
#pragma unroll
      for (int r = 0; r < 4; ++r) {
        float ig = sigf_(acc[m][0][r]);
        float fg = sigf_(acc[m][1][r]);
        float gg = tanhf_(acc[m][2][r]);
        float og = sigf_(acc[m][3][r]);
        float c = fg * c1v[m][r] + ig * gg;
        c1v[m][r] = c;
        hn[m][r] = f2bf(og * tanhf_(c));
      }
    __syncthreads();  // everyone done reading old h1s
#pragma unroll
    for (int m = 0; m < 2; ++m)
#pragma unroll
      for (int r = 0; r < 4; ++r)
        *(unsigned short*)(h1s + haddr(m * 16 + l4 * 4 + r, (wave * 16 + l15) * 2)) = hn[m][r];
    __syncthreads();  // new h1s visible

    // ==== heads: 32 lanes per row, row = wave*2 + (lane>>5)
    float p0 = 0.f, p1 = 0.f;
    const float* hw = headsW + (size_t)t * 512;
#pragma unroll
    for (int jj = 0; jj < 8; ++jj) {
      int j = l31 + jj * 32;
      float h = bf2f(*(const unsigned short*)(h1s + haddr(hrow, j * 2)));
      float2 w = *(const float2*)(hw + j * 2);
      p0 = fmaf(h, w.x, p0);
      p1 = fmaf(h, w.y, p1);
    }
#pragma unroll
    for (int mm = 1; mm < 32; mm <<= 1) {
      p0 += __shfl_xor(p0, mm, 64);
      p1 += __shfl_xor(p1, mm, 64);
    }
    float l0 = p0 + headsb[t * 2 + 0], l1 = p1 + headsb[t * 2 + 1];
    float mx = fmaxf(l0, l1);
    float e0 = __expf(l0 - mx), e1 = __expf(l1 - mx);
    float Z = e0 + e1;
    float lse = mx + __logf(Z);
    float lp0 = l0 - lse, lp1 = l1 - lse;
    float ent = -(e0 * lp0 + e1 * lp1) / Z;
    int a = (hmask >> t) & 1;
    float lp = a ? lp1 : lp0;
    if (l31 == 0) {
      int rowg = b0 + hrow;
      out[2 * B_ + (size_t)rowg * D_ + t] = tlp;  // prefix BEFORE adding
      out[2 * B_ + B_ * D_ + (size_t)rowg * D_ + t] = ent;
    }
    tlp += lp;
    tent += ent;
  }
  if (l31 == 0) {
    int rowg = b0 + hrow;
    out[rowg] = tlp;
    out[B_ + rowg] = tent;
  }
}

// ---------------- launcher ----------------

extern "C" void kernel_launch(void* const* d_in, const int* in_sizes, int n_in,
                              void* d_out, int out_size, void* d_ws, size_t ws_size,
                              hipStream_t stream) {
  const float* states = (const float*)d_in[0];
  const int* actions = (const int*)d_in[1];
  const float* se_W = (const float*)d_in[2];
  const float* se_b = (const float*)d_in[3];
  const float* aemb = (const float*)d_in[4];
  const float* W_ih0 = (const float*)d_in[5];
  const float* W_hh0 = (const float*)d_in[6];
  const float* b_ih0 = (const float*)d_in[7];
  const float* b_hh0 = (const float*)d_in[8];
  const float* W_ih1 = (const float*)d_in[9];
  const float* W_hh1 = (const float*)d_in[10];
  const float* b_ih1 = (const float*)d_in[11];
  const float* b_hh1 = (const float*)d_in[12];
  const float* headsW = (const float*)d_in[13];
  const float* headsb = (const float*)d_in[14];
  float* out = (float*)d_out;
  char* ws = (char*)d_ws;

  unsigned short* seWP  = (unsigned short*)(ws + 0);        // 131072 B
  unsigned short* W0sP  = (unsigned short*)(ws + 131072);   // 524288 B each
  unsigned short* Whh0P = (unsigned short*)(ws + 655360);
  unsigned short* Wih1P = (unsigned short*)(ws + 1179648);
  unsigned short* Whh1P = (unsigned short*)(ws + 1703936);
  float* ptabw          = (float*)(ws + 2228224);
  unsigned* amaskw      = (unsigned*)(ws + 2240512);

  hipLaunchKernelGGL(packB_k, dim3(32), dim3(256), 0, stream, se_W, seWP, 256, 256, 0);
  hipLaunchKernelGGL(packB_k, dim3(128), dim3(256), 0, stream, W_ih0, W0sP, 1024, 288, 0);
  hipLaunchKernelGGL(packB_k, dim3(128), dim3(256), 0, stream, W_hh0, Whh0P, 1024, 256, 0);
  hipLaunchKernelGGL(packB_k, dim3(128), dim3(256), 0, stream, W_ih1, Wih1P, 1024, 256, 0);
  hipLaunchKernelGGL(packB_k, dim3(128), dim3(256), 0, stream, W_hh1, Whh1P, 1024, 256, 0);
  hipLaunchKernelGGL(ptab_k, dim3(4), dim3(256), 0, stream, aemb, W_ih0, ptabw);
  hipLaunchKernelGGL(actmask_k, dim3(32), dim3(256), 0, stream, actions, amaskw);
  hipLaunchKernelGGL(actor_main, dim3(B_ / BT), dim3(NTH), 0, stream,
                     states, seWP, se_b, W0sP, b_ih0, b_hh0, Whh0P, Wih1P, Whh1P,
                     b_ih1, b_hh1, ptabw, amaskw, headsW, headsb, out);
}